// Round 4
// baseline (177.603 us; speedup 1.0000x reference)
//
#include <hip/hip_runtime.h>
#include <hip/hip_bf16.h>

#define H_ 96
#define W_ 96
#define HW_ 9216
#define C_ 256
#define B_ 2
#define KO_ 27
#define NPX_ 18432   // B*HW
#define EPS_ 1e-5f

typedef unsigned short u16;
typedef unsigned short ushort8 __attribute__((ext_vector_type(8)));
typedef short short8v __attribute__((ext_vector_type(8)));
typedef float float4v __attribute__((ext_vector_type(4)));

__device__ __forceinline__ float b2f(u16 u) {
    return __uint_as_float(((unsigned int)u) << 16);
}
__device__ __forceinline__ u16 f2b(float f) {
    __hip_bfloat16 h = __float2bfloat16(f);
    union { __hip_bfloat16 h; u16 u; } cv; cv.h = h; return cv.u;
}
__device__ __forceinline__ unsigned int pack2(float a, float b) {
    union { __hip_bfloat162 h; unsigned int u; } cv;
    cv.h = __float22bfloat162_rn(make_float2(a, b));
    return cv.u;
}
// async global->LDS, 16B per lane; LDS dest = uniform base + lane*16
__device__ __forceinline__ void glds16(const u16* g, u16* l) {
    __builtin_amdgcn_global_load_lds(
        (const __attribute__((address_space(1))) void*)g,
        (__attribute__((address_space(3))) void*)l, 16, 0, 0);
}

// ---------------- kernel 1: weight repacks + BN fold -------
// WQ layout is PRE-SWIZZLED for conflict-free ds_read_b128 in fused_kernel:
// physical WQ[ch*8192 + o*32 + cpa] holds logical w_conv[o][c][k] with
// c = (ch&7)*32 + (cpa ^ ((o&3)<<3)), k = ch>>3.  (rule #21: glds16 writes
// LDS linearly, so the read-side XOR swizzle is baked into the source.)
// WO[(tap*8+cg)*1024 + o*32 + cp] = bf16(w_off[o][c][tap]) (o<27, else 0)
__global__ __launch_bounds__(256) void prep_w_kernel(
    const float* __restrict__ w_conv, const float* __restrict__ w_off,
    const float* __restrict__ b_conv,
    const float* __restrict__ gamma, const float* __restrict__ beta,
    const float* __restrict__ rmean, const float* __restrict__ rvar,
    float* __restrict__ AB, u16* __restrict__ WQ, u16* __restrict__ WO)
{
    if (blockIdx.x == 0) {
        int o = threadIdx.x;
        float sc = gamma[o] * rsqrtf(rvar[o] + EPS_);
        AB[o] = sc;
        AB[256 + o] = beta[o] + (b_conv[o] - rmean[o]) * sc;
    }
    if (blockIdx.x < 2304) {
        int idx = blockIdx.x * 256 + threadIdx.x;   // 589824 total
        int ch = idx >> 13;          // chunk = tap*8 + c/32
        int o  = (idx >> 5) & 255;
        int cpa = idx & 31;
        int cp  = cpa ^ ((o & 3) << 3);             // read-swizzle inverse
        int c  = ((ch & 7) << 5) + cp;
        int k  = ch >> 3;
        WQ[idx] = f2b(w_conv[(o * C_ + c) * 9 + k]);
    } else {
        int j = (blockIdx.x - 2304) * 256 + threadIdx.x;  // 73728 total
        int ch = j >> 10;
        int o  = (j >> 5) & 31;
        int cp = j & 31;
        int c  = ((ch & 7) << 5) + cp;
        int k  = ch >> 3;
        WO[j] = (o < KO_) ? f2b(w_off[(o * C_ + c) * 9 + k]) : (u16)0;
    }
}

// ---------------- kernel 2: x NCHW f32 -> NHWC bf16 ----------------
__global__ __launch_bounds__(256) void xt_kernel(const float* __restrict__ x,
                                                 u16* __restrict__ XT)
{
    __shared__ u16 ls[32][100];
    int h  = blockIdx.x;
    int cg = blockIdx.y & 7;
    int b  = blockIdx.y >> 3;
    int c0 = cg * 32;
    for (int e = threadIdx.x; e < 32 * W_; e += 256) {
        int ci = e / W_, w = e % W_;
        ls[ci][w] = f2b(x[((b * C_ + c0 + ci) * H_ + h) * W_ + w]);
    }
    __syncthreads();
    for (int e = threadIdx.x; e < 32 * W_; e += 256) {
        int w = e >> 5, ci = e & 31;
        XT[((b * H_ + h) * W_ + w) * C_ + c0 + ci] = ls[ci][w];
    }
}

// ---------------- kernel 3: offset GEMM -> OFF[n*32+o] (f32) ---------------
// OFF[n*32+o]: o<18 raw offsets (dy,dx interleaved), 18..26 sigmoid(mask).
__global__ __launch_bounds__(256) void offsets_kernel(
    const u16* __restrict__ XT, const u16* __restrict__ WO,
    const float* __restrict__ b_off, float* __restrict__ OFF)
{
    __shared__ float red[4][32][16];

    const int tid = threadIdx.x;
    const int b  = blockIdx.y;
    const int p0 = blockIdx.x * 16;
    const int h  = p0 / W_;            // 16 px all on one row
    const int w0 = p0 % W_;

    const int wave = tid >> 6;
    const int lane = tid & 63;
    const int quad = lane >> 4;
    const int l15  = lane & 15;

    // 27x2304 offset GEMM, K split across 4 waves
    {
        const int pw = w0 + l15;
        float4v acc0 = float4v{0.f,0.f,0.f,0.f};
        float4v acc1 = float4v{0.f,0.f,0.f,0.f};
        int basec = 0; bool vld = true; int curtap = -1;
        auto set_tap = [&](int tap) {
            int py  = h + tap / 3 - 1;
            int pxl = pw + tap % 3 - 1;
            vld = ((unsigned)py < (unsigned)H_) && ((unsigned)pxl < (unsigned)W_);
            int pyc = min(max(py, 0), H_ - 1);
            int pxc = min(max(pxl, 0), W_ - 1);
            basec = ((b * H_ + pyc) * W_ + pxc) * C_ + quad * 8;
        };
        auto bload = [&](int c32) -> ushort8 {
            ushort8 v = *(const ushort8*)(XT + basec + (c32 & 7) * 32);
#pragma unroll
            for (int j = 0; j < 8; j++) v[j] = vld ? v[j] : (u16)0;
            return v;
        };
        const int c0 = wave * 18, c1 = c0 + 18;
        curtap = c0 >> 3;
        set_tap(curtap);
        ushort8 bq = bload(c0);
        short8v wa = *(const short8v*)(WO + c0 * 1024 + l15 * 32 + quad * 8);
        short8v wb = *(const short8v*)(WO + c0 * 1024 + l15 * 32 + quad * 8 + 512);
        for (int i = c0; i < c1; ++i) {
            ushort8 bc = bq;
            short8v wac = wa, wbc = wb;
            int nx = i + 1;
            if (nx < c1) {
                int t = nx >> 3;
                if (t != curtap) { set_tap(t); curtap = t; }
                bq = bload(nx);
                wa = *(const short8v*)(WO + nx * 1024 + l15 * 32 + quad * 8);
                wb = *(const short8v*)(WO + nx * 1024 + l15 * 32 + quad * 8 + 512);
            }
            union { ushort8 u; short8v s; } cb; cb.u = bc;
            acc0 = __builtin_amdgcn_mfma_f32_16x16x32_bf16(wac, cb.s, acc0, 0, 0, 0);
            acc1 = __builtin_amdgcn_mfma_f32_16x16x32_bf16(wbc, cb.s, acc1, 0, 0, 0);
        }
#pragma unroll
        for (int r = 0; r < 4; ++r) {
            red[wave][quad * 4 + r][l15]      = acc0[r];
            red[wave][16 + quad * 4 + r][l15] = acc1[r];
        }
    }
    __syncthreads();
    const int n_base = b * HW_ + p0;
#pragma unroll
    for (int rep = 0; rep < 2; ++rep) {
        int o  = (tid >> 4) + rep * 16;   // 0..31
        int px = tid & 15;
        if (o < KO_) {
            float v = red[0][o][px] + red[1][o][px] + red[2][o][px] + red[3][o][px]
                    + b_off[o];
            OFF[(size_t)(n_base + px) * 32 + o] =
                (o < 18) ? v : 1.f / (1.f + expf(-v));
        }
    }
}

// ---------------- kernel 4: FUSED gather+lerp+GEMM+BN+relu+residual --------
// Pipelined 2-barrier K-loop (36 chunks of 64 ch): chunk ch+1's gathers
// (->regs) and glds16 A-stage are issued in P3 of chunk ch, after the
// read-barrier (single sA buffer stays safe), hidden under the MFMA cluster
// + next lerp. Fragment reads use XOR swizzle slot^=(row&3) — sA via
// pre-swizzled WQ (rule #21), sB swizzled on both write and read.
__global__ __launch_bounds__(256) void fused_kernel(
    const float* __restrict__ x, const u16* __restrict__ XT,
    const float* __restrict__ OFF, const u16* __restrict__ WQ,
    const float* __restrict__ AB, float* __restrict__ out)
{
    __shared__ __align__(16) u16 sA[16384];   // 32 KB [cc][o 256][cp 32] swz
    __shared__ __align__(16) u16 sB[2048];    //  4 KB [cc][px 32][cp 32] swz
    __shared__ float offv[32][32];            //  4 KB  (total 40960 = 4/CU)

    const int tid = threadIdx.x;
    const int wave = tid >> 6;
    const int lane = tid & 63;
    const int quad = lane >> 4;
    const int l15  = lane & 15;
    const int qx   = (quad ^ (l15 & 3)) << 3;   // swizzled 8-u16 slot

    // 576 = 8 * 72 -> bijective XCD swizzle; n-contiguous chunks per XCD
    const int bid = blockIdx.x;
    const int swz = (bid & 7) * 72 + (bid >> 3);
    const int n0  = swz * 32;
    const int b   = n0 / HW_;
    const int p0  = n0 - b * HW_;
    const int h   = p0 / W_;            // 32-px tile fits one row (96 = 3*32)
    const int w0  = p0 % W_;

    // load OFF tile (32 px x 32 f32) -> LDS
    {
        int px = tid >> 3, q4 = (tid & 7) * 4;
        float4 v = *(const float4*)(OFF + (size_t)(n0 + px) * 32 + q4);
        *(float4*)&offv[px][q4] = v;
    }
    __syncthreads();

    float4v acc[4][2];
#pragma unroll
    for (int i = 0; i < 4; i++)
#pragma unroll
        for (int jj = 0; jj < 2; jj++)
            acc[i][jj] = float4v{0.f, 0.f, 0.f, 0.f};

    const int le8 = lane * 8;       // lane offset within a 1KB staging unit
    const int wo  = wave * 64;      // wave's o-slice

    // producer identity: px = tid>>3 (32 rows), pj = tid&7 (8 ch-octets)
    const int ppx = tid >> 3;
    const int pj  = tid & 7;
    const int sboff = (pj >> 2) * 1024 + ppx * 32
                    + (((pj & 3) ^ (ppx & 3)) << 3);      // swizzled write

    float fn0, fn1, fn2, fn3;       // weights for tap of in-flight gathers
    int a00, a01, a10, a11;         // gather base addrs for that tap

    auto tap_setup = [&](int tap) {
        float dy = offv[ppx][2 * tap];
        float dx = offv[ppx][2 * tap + 1];
        float m  = offv[ppx][18 + tap];
        float py  = (float)(h + tap / 3 - 1) + dy;
        float pxx = (float)(w0 + ppx + tap % 3 - 1) + dx;
        float y0f = floorf(py), x0f = floorf(pxx);
        float ly = py - y0f, lx = pxx - x0f;
        int y0 = (int)y0f, x0i = (int)x0f;
        int y1 = y0 + 1, x1 = x0i + 1;
        bool vy0 = (unsigned)y0 < (unsigned)H_;
        bool vy1 = (unsigned)y1 < (unsigned)H_;
        bool vx0 = (unsigned)x0i < (unsigned)W_;
        bool vx1 = (unsigned)x1 < (unsigned)W_;
        fn0 = (vy0 && vx0) ? (1.f - ly) * (1.f - lx) * m : 0.f;
        fn1 = (vy0 && vx1) ? (1.f - ly) * lx * m : 0.f;
        fn2 = (vy1 && vx0) ? ly * (1.f - lx) * m : 0.f;
        fn3 = (vy1 && vx1) ? ly * lx * m : 0.f;
        int y0c = min(max(y0, 0), H_ - 1), y1c = min(max(y1, 0), H_ - 1);
        int x0c = min(max(x0i, 0), W_ - 1), x1c = min(max(x1, 0), W_ - 1);
        a00 = ((b * H_ + y0c) * W_ + x0c) * C_;
        a01 = ((b * H_ + y0c) * W_ + x1c) * C_;
        a10 = ((b * H_ + y1c) * W_ + x0c) * C_;
        a11 = ((b * H_ + y1c) * W_ + x1c) * C_;
    };

    // ---- prologue: tap 0, chunk 0 gathers + A-stage ----
    tap_setup(0);
    float fc0 = fn0, fc1 = fn1, fc2 = fn2, fc3 = fn3;
    ushort8 gc00 = *(const ushort8*)(XT + a00 + pj * 8);
    ushort8 gc01 = *(const ushort8*)(XT + a01 + pj * 8);
    ushort8 gc10 = *(const ushort8*)(XT + a10 + pj * 8);
    ushort8 gc11 = *(const ushort8*)(XT + a11 + pj * 8);
#pragma unroll
    for (int i = 0; i < 8; ++i) {
        int unit = i * 4 + wave;                 // 0..31, wave-uniform
        int cc = unit >> 4;
        glds16(WQ + (size_t)cc * 8192 + (unit & 15) * 512 + le8,
               &sA[unit * 512]);
    }
    ushort8 gn00{}, gn01{}, gn10{}, gn11{};

#pragma unroll 4
    for (int ch = 0; ch < 36; ++ch) {
        // ---- P1: lerp current gathers -> sB (swizzled) ----
        {
            float v[8];
#pragma unroll
            for (int t = 0; t < 8; t++)
                v[t] = fc0 * b2f(gc00[t]) + fc1 * b2f(gc01[t])
                     + fc2 * b2f(gc10[t]) + fc3 * b2f(gc11[t]);
            uint4 sv;
            sv.x = pack2(v[0], v[1]);
            sv.y = pack2(v[2], v[3]);
            sv.z = pack2(v[4], v[5]);
            sv.w = pack2(v[6], v[7]);
            *(uint4*)&sB[sboff] = sv;
        }
        asm volatile("s_waitcnt vmcnt(0) lgkmcnt(0)" ::: "memory");
        __builtin_amdgcn_s_barrier();            // sA + sB for ch ready

        // ---- P2: fragment reads (swizzled slots -> 2 lanes/bank) ----
        short8v af[2][4], bfr[2][2];
#pragma unroll
        for (int cc = 0; cc < 2; ++cc) {
#pragma unroll
            for (int mt = 0; mt < 4; ++mt)
                af[cc][mt] = *(const short8v*)
                    &sA[cc * 8192 + (wo + mt * 16 + l15) * 32 + qx];
#pragma unroll
            for (int nt = 0; nt < 2; ++nt)
                bfr[cc][nt] = *(const short8v*)
                    &sB[cc * 1024 + (nt * 16 + l15) * 32 + qx];
        }
        asm volatile("s_waitcnt lgkmcnt(0)" ::: "memory");
        __builtin_amdgcn_s_barrier();            // all reads done; sA free

        // ---- P3: prefetch chunk ch+1 (gathers + A-stage), then MFMA ----
        if (ch < 35) {
            const int chn = ch + 1, tapn = chn >> 2, qn = chn & 3;
            if (qn == 0) tap_setup(tapn);
            const int cb = qn * 64 + pj * 8;
            gn00 = *(const ushort8*)(XT + a00 + cb);
            gn01 = *(const ushort8*)(XT + a01 + cb);
            gn10 = *(const ushort8*)(XT + a10 + cb);
            gn11 = *(const ushort8*)(XT + a11 + cb);
#pragma unroll
            for (int i = 0; i < 8; ++i) {
                int unit = i * 4 + wave;
                int cc = unit >> 4;
                glds16(WQ + (size_t)(tapn * 8 + qn * 2 + cc) * 8192
                          + (unit & 15) * 512 + le8,
                       &sA[unit * 512]);
            }
        }
        __builtin_amdgcn_s_setprio(1);
#pragma unroll
        for (int cc = 0; cc < 2; ++cc)
#pragma unroll
            for (int mt = 0; mt < 4; ++mt)
#pragma unroll
                for (int nt = 0; nt < 2; ++nt)
                    acc[mt][nt] = __builtin_amdgcn_mfma_f32_16x16x32_bf16(
                        af[cc][mt], bfr[cc][nt], acc[mt][nt], 0, 0, 0);
        __builtin_amdgcn_s_setprio(0);
        gc00 = gn00; gc01 = gn01; gc10 = gn10; gc11 = gn11;
        fc0 = fn0; fc1 = fn1; fc2 = fn2; fc3 = fn3;
    }

    // epilogue: BN fold + relu + residual
    const float* Ao = AB;
    const float* Bo = AB + 256;
#pragma unroll
    for (int mt = 0; mt < 4; mt++) {
#pragma unroll
        for (int nt = 0; nt < 2; nt++) {
            int pix = p0 + nt * 16 + l15;
#pragma unroll
            for (int r = 0; r < 4; r++) {
                int o = wo + mt * 16 + quad * 4 + r;
                float v = acc[mt][nt][r] * Ao[o] + Bo[o];
                v = fmaxf(v, 0.f);
                int gi = (b * C_ + o) * HW_ + pix;
                out[gi] = x[gi] + v;
            }
        }
    }
}

extern "C" void kernel_launch(void* const* d_in, const int* in_sizes, int n_in,
                              void* d_out, int out_size, void* d_ws, size_t ws_size,
                              hipStream_t stream)
{
    (void)in_sizes; (void)n_in; (void)out_size; (void)ws_size;
    const float* x      = (const float*)d_in[0];
    const float* w_off  = (const float*)d_in[1];
    const float* b_off  = (const float*)d_in[2];
    const float* w_conv = (const float*)d_in[3];
    const float* b_conv = (const float*)d_in[4];
    const float* gamma  = (const float*)d_in[5];
    const float* beta   = (const float*)d_in[6];
    const float* rmean  = (const float*)d_in[7];
    const float* rvar   = (const float*)d_in[8];
    float* out = (float*)d_out;

    float* ws = (float*)d_ws;
    float* AB = ws;                            // 512 floats
    u16* WQ = (u16*)(AB + 512);                // 589824 u16
    u16* WO = WQ + 589824;                     // 73728 u16
    u16* XT = WO + 73728;                      // 4718592 u16
    float* OFF = (float*)(XT + 4718592);       // 18432*32 f32 = 2.36 MB

    prep_w_kernel<<<2592, 256, 0, stream>>>(w_conv, w_off, b_conv, gamma, beta,
                                            rmean, rvar, AB, WQ, WO);
    xt_kernel<<<dim3(96, 16), 256, 0, stream>>>(x, XT);
    offsets_kernel<<<dim3(576, 2), 256, 0, stream>>>(XT, WO, b_off, OFF);
    fused_kernel<<<576, 256, 0, stream>>>(x, XT, OFF, WQ, AB, out);
}

// Round 5
// 174.957 us; speedup vs baseline: 1.0151x; 1.0151x over previous
//
#include <hip/hip_runtime.h>
#include <hip/hip_bf16.h>

#define H_ 96
#define W_ 96
#define HW_ 9216
#define C_ 256
#define B_ 2
#define KO_ 27
#define NPX_ 18432   // B*HW
#define EPS_ 1e-5f

typedef unsigned short u16;
typedef unsigned short ushort8 __attribute__((ext_vector_type(8)));
typedef unsigned short ushort4v __attribute__((ext_vector_type(4)));
typedef short short8v __attribute__((ext_vector_type(8)));
typedef float float4v __attribute__((ext_vector_type(4)));

__device__ __forceinline__ float b2f(u16 u) {
    return __uint_as_float(((unsigned int)u) << 16);
}
__device__ __forceinline__ u16 f2b(float f) {
    __hip_bfloat16 h = __float2bfloat16(f);
    union { __hip_bfloat16 h; u16 u; } cv; cv.h = h; return cv.u;
}
__device__ __forceinline__ unsigned int pack2(float a, float b) {
    union { __hip_bfloat162 h; unsigned int u; } cv;
    cv.h = __float22bfloat162_rn(make_float2(a, b));
    return cv.u;
}

// ---------------- kernel 1: weights + BN fold + x transpose (merged) -------
// WQ[ch*8192 + o*32 + cp] = bf16(w_conv[o][c][k]), c=(ch&7)*32+cp, k=ch>>3
// WO[c32*1024 + o*32 + cp] = bf16(w_off[o][c][tap]) (o<27, else 0)
// XT[((b*96+h)*96+w)*256 + c] = bf16(x[b][c][h][w])
__global__ __launch_bounds__(256) void prep_kernel(
    const float* __restrict__ x,
    const float* __restrict__ w_conv, const float* __restrict__ w_off,
    const float* __restrict__ b_conv,
    const float* __restrict__ gamma, const float* __restrict__ beta,
    const float* __restrict__ rmean, const float* __restrict__ rvar,
    float* __restrict__ AB, u16* __restrict__ WQ, u16* __restrict__ WO,
    u16* __restrict__ XT)
{
    __shared__ u16 ls[32][100];
    const int bx = blockIdx.x;
    if (bx < 2304) {
        if (bx == 0) {
            int o = threadIdx.x;
            float sc = gamma[o] * rsqrtf(rvar[o] + EPS_);
            AB[o] = sc;
            AB[256 + o] = beta[o] + (b_conv[o] - rmean[o]) * sc;
        }
        int idx = bx * 256 + threadIdx.x;   // 589824 total
        int ch = idx >> 13;
        int o  = (idx >> 5) & 255;
        int cp = idx & 31;
        int c  = ((ch & 7) << 5) + cp;
        int k  = ch >> 3;
        WQ[idx] = f2b(w_conv[(o * C_ + c) * 9 + k]);
    } else if (bx < 2592) {
        int j = (bx - 2304) * 256 + threadIdx.x;  // 73728 total
        int ch = j >> 10;
        int o  = (j >> 5) & 31;
        int cp = j & 31;
        int c  = ((ch & 7) << 5) + cp;
        int k  = ch >> 3;
        WO[j] = (o < KO_) ? f2b(w_off[(o * C_ + c) * 9 + k]) : (u16)0;
    } else {
        int bid = bx - 2592;           // 0..1535
        int h  = bid % 96;
        int by = bid / 96;
        int cg = by & 7;
        int b  = by >> 3;
        int c0 = cg * 32;
        for (int e = threadIdx.x; e < 32 * W_; e += 256) {
            int ci = e / W_, w = e % W_;
            ls[ci][w] = f2b(x[((b * C_ + c0 + ci) * H_ + h) * W_ + w]);
        }
        __syncthreads();
        // 8B stores: unit = w*8 + g4 (c fastest across lanes -> 64B segments)
        for (int u = threadIdx.x; u < 768; u += 256) {
            int g4 = u & 7, w = u >> 3;
            ushort4v v;
#pragma unroll
            for (int t = 0; t < 4; t++) v[t] = ls[g4 * 4 + t][w];
            *(ushort4v*)&XT[((b * H_ + h) * W_ + w) * C_ + c0 + g4 * 4] = v;
        }
    }
}

// ---------------- kernel 2: FULLY FUSED ------------------------------------
// Per block (32 px, one row segment): prologue computes this block's own
// 27x32 offset GEMM (K=2304 split across 4 waves, MFMA) -> offv.
// Main loop (36 chunks of 64 ch): A-fragments loaded DIRECTLY from
// L2-resident WQ into VGPRs (compiler counted-vmcnt pipelining, no LDS
// staging, no vmcnt drain anywhere); B produced by bilinear gather+lerp
// into 4KB sB; raw s_barrier + lgkmcnt(0) only. Epilogue BN+relu+residual.
__global__ __launch_bounds__(256) void fused_kernel(
    const float* __restrict__ x, const u16* __restrict__ XT,
    const u16* __restrict__ WO, const float* __restrict__ b_off,
    const u16* __restrict__ WQ, const float* __restrict__ AB,
    float* __restrict__ out)
{
    __shared__ float red[4][2][32][17];          // 17.4 KB (prologue only)
    __shared__ __align__(16) u16 sB[2048];       //  4 KB [cc][px32][slot32]
    __shared__ float offv[32][36];               //  4.6 KB, padded rows

    const int tid  = threadIdx.x;
    const int wave = tid >> 6;
    const int lane = tid & 63;
    const int quad = lane >> 4;
    const int l15  = lane & 15;

    // 576 = 8 * 72 -> bijective XCD swizzle (gather locality per XCD L2)
    const int bid = blockIdx.x;
    const int swz = (bid & 7) * 72 + (bid >> 3);
    const int n0  = swz * 32;
    const int b   = n0 / HW_;
    const int p0  = n0 - b * HW_;
    const int h   = p0 / W_;            // 32-px tile fits one row
    const int w0  = p0 % W_;

    // ---------- prologue: offsets GEMM for this block's 32 px ----------
    {
        float4v oa[2][2];
#pragma unroll
        for (int ph = 0; ph < 2; ph++)
#pragma unroll
            for (int hh = 0; hh < 2; hh++)
                oa[ph][hh] = float4v{0.f, 0.f, 0.f, 0.f};

        int basec0 = 0, basec1 = 0; bool vld0 = true, vld1 = true;
        auto oset = [&](int tap) {
            int py = h + tap / 3 - 1;
            bool vy = (unsigned)py < (unsigned)H_;
            int pyc = min(max(py, 0), H_ - 1);
            int rowb = (b * H_ + pyc) * W_;
            {
                int pxl = w0 + l15 + tap % 3 - 1;
                vld0 = vy && ((unsigned)pxl < (unsigned)W_);
                basec0 = (rowb + min(max(pxl, 0), W_ - 1)) * C_ + quad * 8;
            }
            {
                int pxl = w0 + 16 + l15 + tap % 3 - 1;
                vld1 = vy && ((unsigned)pxl < (unsigned)W_);
                basec1 = (rowb + min(max(pxl, 0), W_ - 1)) * C_ + quad * 8;
            }
        };
        auto bld0 = [&](int c32) -> ushort8 {
            ushort8 v = *(const ushort8*)(XT + basec0 + (c32 & 7) * 32);
#pragma unroll
            for (int j = 0; j < 8; j++) v[j] = vld0 ? v[j] : (u16)0;
            return v;
        };
        auto bld1 = [&](int c32) -> ushort8 {
            ushort8 v = *(const ushort8*)(XT + basec1 + (c32 & 7) * 32);
#pragma unroll
            for (int j = 0; j < 8; j++) v[j] = vld1 ? v[j] : (u16)0;
            return v;
        };
        const int i0 = wave * 18, i1 = i0 + 18;
        int curtap = i0 >> 3;
        oset(curtap);
        ushort8 b0 = bld0(i0), b1 = bld1(i0);
        short8v wa = *(const short8v*)(WO + i0 * 1024 + l15 * 32 + quad * 8);
        short8v wb = *(const short8v*)(WO + i0 * 1024 + l15 * 32 + quad * 8 + 512);
        for (int i = i0; i < i1; ++i) {
            ushort8 c0v = b0, c1v = b1;
            short8v wac = wa, wbc = wb;
            int nx = i + 1;
            if (nx < i1) {
                int t = nx >> 3;
                if (t != curtap) { oset(t); curtap = t; }
                b0 = bld0(nx); b1 = bld1(nx);
                wa = *(const short8v*)(WO + nx * 1024 + l15 * 32 + quad * 8);
                wb = *(const short8v*)(WO + nx * 1024 + l15 * 32 + quad * 8 + 512);
            }
            union { ushort8 u; short8v s; } u0, u1; u0.u = c0v; u1.u = c1v;
            oa[0][0] = __builtin_amdgcn_mfma_f32_16x16x32_bf16(wac, u0.s, oa[0][0], 0, 0, 0);
            oa[0][1] = __builtin_amdgcn_mfma_f32_16x16x32_bf16(wbc, u0.s, oa[0][1], 0, 0, 0);
            oa[1][0] = __builtin_amdgcn_mfma_f32_16x16x32_bf16(wac, u1.s, oa[1][0], 0, 0, 0);
            oa[1][1] = __builtin_amdgcn_mfma_f32_16x16x32_bf16(wbc, u1.s, oa[1][1], 0, 0, 0);
        }
#pragma unroll
        for (int r = 0; r < 4; ++r) {
            red[wave][0][quad * 4 + r][l15]      = oa[0][0][r];
            red[wave][0][16 + quad * 4 + r][l15] = oa[0][1][r];
            red[wave][1][quad * 4 + r][l15]      = oa[1][0][r];
            red[wave][1][16 + quad * 4 + r][l15] = oa[1][1][r];
        }
    }
    __syncthreads();
    for (int u = tid; u < 1024; u += 256) {
        int px = u & 31, o = u >> 5;
        if (o < KO_) {
            int ph = px >> 4, pp = px & 15;
            float v = red[0][ph][o][pp] + red[1][ph][o][pp]
                    + red[2][ph][o][pp] + red[3][ph][o][pp] + b_off[o];
            offv[px][o] = (o < 18) ? v : 1.f / (1.f + expf(-v));
        }
    }
    __syncthreads();

    // ---------- main loop ----------
    float4v acc[4][2];
#pragma unroll
    for (int i = 0; i < 4; i++)
#pragma unroll
        for (int jj = 0; jj < 2; jj++)
            acc[i][jj] = float4v{0.f, 0.f, 0.f, 0.f};

    const int wo  = wave * 64;
    const int ppx = tid >> 3;
    const int pj  = tid & 7;
    const int sboff = (pj >> 2) * 1024 + ppx * 32 + (((pj & 3) ^ (ppx & 3)) << 3);
    const int bslot = (quad ^ (l15 & 3)) << 3;

    float fc0, fc1, fc2, fc3, fn0, fn1, fn2, fn3;
    int a00, a01, a10, a11;

    auto tap_setup = [&](int tap) {
        float dy = offv[ppx][2 * tap];
        float dx = offv[ppx][2 * tap + 1];
        float m  = offv[ppx][18 + tap];
        float py  = (float)(h + tap / 3 - 1) + dy;
        float pxx = (float)(w0 + ppx + tap % 3 - 1) + dx;
        float y0f = floorf(py), x0f = floorf(pxx);
        float ly = py - y0f, lx = pxx - x0f;
        int y0 = (int)y0f, x0i = (int)x0f;
        int y1 = y0 + 1, x1 = x0i + 1;
        bool vy0 = (unsigned)y0 < (unsigned)H_;
        bool vy1 = (unsigned)y1 < (unsigned)H_;
        bool vx0 = (unsigned)x0i < (unsigned)W_;
        bool vx1 = (unsigned)x1 < (unsigned)W_;
        fn0 = (vy0 && vx0) ? (1.f - ly) * (1.f - lx) * m : 0.f;
        fn1 = (vy0 && vx1) ? (1.f - ly) * lx * m : 0.f;
        fn2 = (vy1 && vx0) ? ly * (1.f - lx) * m : 0.f;
        fn3 = (vy1 && vx1) ? ly * lx * m : 0.f;
        int y0c = min(max(y0, 0), H_ - 1), y1c = min(max(y1, 0), H_ - 1);
        int x0c = min(max(x0i, 0), W_ - 1), x1c = min(max(x1, 0), W_ - 1);
        a00 = ((b * H_ + y0c) * W_ + x0c) * C_;
        a01 = ((b * H_ + y0c) * W_ + x1c) * C_;
        a10 = ((b * H_ + y1c) * W_ + x0c) * C_;
        a11 = ((b * H_ + y1c) * W_ + x1c) * C_;
    };

    tap_setup(0);
    fc0 = fn0; fc1 = fn1; fc2 = fn2; fc3 = fn3;
    ushort8 gc00 = *(const ushort8*)(XT + a00 + pj * 8);
    ushort8 gc01 = *(const ushort8*)(XT + a01 + pj * 8);
    ushort8 gc10 = *(const ushort8*)(XT + a10 + pj * 8);
    ushort8 gc11 = *(const ushort8*)(XT + a11 + pj * 8);
    ushort8 gn00{}, gn01{}, gn10{}, gn11{};

#pragma unroll 1
    for (int ch = 0; ch < 36; ++ch) {
        const int tap = ch >> 2, q = ch & 3;

        // ---- A(ch): direct global->VGPR fragment loads (L2-resident WQ) ----
        short8v af[2][4];
        const u16* wq0 = WQ + (size_t)(tap * 8 + q * 2) * 8192
                       + (wo + l15) * 32 + quad * 8;
#pragma unroll
        for (int cc = 0; cc < 2; ++cc)
#pragma unroll
            for (int mt = 0; mt < 4; ++mt)
                af[cc][mt] = *(const short8v*)(wq0 + cc * 8192 + mt * 512);

        // ---- P1: lerp current gathers -> sB (swizzled write) ----
        {
            float v[8];
#pragma unroll
            for (int t = 0; t < 8; t++)
                v[t] = fc0 * b2f(gc00[t]) + fc1 * b2f(gc01[t])
                     + fc2 * b2f(gc10[t]) + fc3 * b2f(gc11[t]);
            uint4 sv;
            sv.x = pack2(v[0], v[1]);
            sv.y = pack2(v[2], v[3]);
            sv.z = pack2(v[4], v[5]);
            sv.w = pack2(v[6], v[7]);
            *(uint4*)&sB[sboff] = sv;
        }

        // ---- G(ch+1) prefetch ----
        if (ch < 35) {
            const int chn = ch + 1, tapn = chn >> 2, qn = chn & 3;
            if (qn == 0) tap_setup(tapn);
            const int cb = qn * 64 + pj * 8;
            gn00 = *(const ushort8*)(XT + a00 + cb);
            gn01 = *(const ushort8*)(XT + a01 + cb);
            gn10 = *(const ushort8*)(XT + a10 + cb);
            gn11 = *(const ushort8*)(XT + a11 + cb);
        }

        asm volatile("s_waitcnt lgkmcnt(0)" ::: "memory");
        __builtin_amdgcn_s_barrier();            // sB ready (vmcnt NOT drained)

        short8v bfr[2][2];
#pragma unroll
        for (int cc = 0; cc < 2; ++cc)
#pragma unroll
            for (int nt = 0; nt < 2; ++nt)
                bfr[cc][nt] = *(const short8v*)
                    &sB[cc * 1024 + (nt * 16 + l15) * 32 + bslot];

        asm volatile("s_waitcnt lgkmcnt(0)" ::: "memory");
        __builtin_amdgcn_s_barrier();            // sB consumed; safe to rewrite
        __builtin_amdgcn_sched_barrier(0);

        __builtin_amdgcn_s_setprio(1);
#pragma unroll
        for (int cc = 0; cc < 2; ++cc)
#pragma unroll
            for (int mt = 0; mt < 4; ++mt)
#pragma unroll
                for (int nt = 0; nt < 2; ++nt)
                    acc[mt][nt] = __builtin_amdgcn_mfma_f32_16x16x32_bf16(
                        af[cc][mt], bfr[cc][nt], acc[mt][nt], 0, 0, 0);
        __builtin_amdgcn_s_setprio(0);

        gc00 = gn00; gc01 = gn01; gc10 = gn10; gc11 = gn11;
        fc0 = fn0; fc1 = fn1; fc2 = fn2; fc3 = fn3;
    }

    // epilogue: BN fold + relu + residual
    const float* Ao = AB;
    const float* Bo = AB + 256;
#pragma unroll
    for (int mt = 0; mt < 4; mt++) {
#pragma unroll
        for (int nt = 0; nt < 2; nt++) {
            int pix = p0 + nt * 16 + l15;
#pragma unroll
            for (int r = 0; r < 4; r++) {
                int o = wo + mt * 16 + quad * 4 + r;
                float v = acc[mt][nt][r] * Ao[o] + Bo[o];
                v = fmaxf(v, 0.f);
                int gi = (b * C_ + o) * HW_ + pix;
                out[gi] = x[gi] + v;
            }
        }
    }
}

extern "C" void kernel_launch(void* const* d_in, const int* in_sizes, int n_in,
                              void* d_out, int out_size, void* d_ws, size_t ws_size,
                              hipStream_t stream)
{
    (void)in_sizes; (void)n_in; (void)out_size; (void)ws_size;
    const float* x      = (const float*)d_in[0];
    const float* w_off  = (const float*)d_in[1];
    const float* b_off  = (const float*)d_in[2];
    const float* w_conv = (const float*)d_in[3];
    const float* b_conv = (const float*)d_in[4];
    const float* gamma  = (const float*)d_in[5];
    const float* beta   = (const float*)d_in[6];
    const float* rmean  = (const float*)d_in[7];
    const float* rvar   = (const float*)d_in[8];
    float* out = (float*)d_out;

    float* ws = (float*)d_ws;
    float* AB = ws;                            // 512 floats
    u16* WQ = (u16*)(AB + 512);                // 589824 u16
    u16* WO = WQ + 589824;                     // 73728 u16
    u16* XT = WO + 73728;                      // 4718592 u16

    prep_kernel<<<4128, 256, 0, stream>>>(x, w_conv, w_off, b_conv, gamma, beta,
                                          rmean, rvar, AB, WQ, WO, XT);
    fused_kernel<<<576, 256, 0, stream>>>(x, XT, WO, b_off, WQ, AB, out);
}